// Round 4
// baseline (1535.669 us; speedup 1.0000x reference)
//
#include <hip/hip_runtime.h>
#include <hip/hip_bf16.h>

#define N_NODES   100000
#define N_EDGES   1600000
#define FDIM      128
#define N_GRAPHS  1024
#define N_CLASSES 32
#define SCAN_BLK  1024
#define M_PAD     100032            // padded rows for 64-row GEMM tiles
#define SLICE_U   (M_PAD * 8)       // uints per 16-feature slice (32B/row)

typedef __attribute__((ext_vector_type(8))) short short8v;
typedef __attribute__((ext_vector_type(4))) float f32x4;

__device__ __forceinline__ float bflo(unsigned u){ union{unsigned i; float f;} c; c.i = u << 16; return c.f; }
__device__ __forceinline__ float bfhi(unsigned u){ union{unsigned i; float f;} c; c.i = u & 0xffff0000u; return c.f; }
__device__ __forceinline__ unsigned short f2bf(float f){
    union{float f; unsigned u;} c{f};
    return (unsigned short)((c.u + 0x7fffu + ((c.u >> 16) & 1u)) >> 16);
}
__device__ __forceinline__ unsigned packbf2(float a, float b){
    return (unsigned)f2bf(a) | ((unsigned)f2bf(b) << 16);
}
__device__ __forceinline__ long long ldnt64(const void* p){
    return __builtin_nontemporal_load((const long long*)p);
}

// ---------------------------------------------------------------------------
// fp32 x[v][128] -> bf16x2 sliced: out[f*SLICE_U + v*8 + off], f=feat/16
__global__ void k_f2bf(const float* __restrict__ in, unsigned* __restrict__ out, int n2) {
    int i = blockIdx.x * blockDim.x + threadIdx.x;
    if (i < n2) {
        float2 v2 = ((const float2*)in)[i];
        int v = i >> 6, jp = i & 63;          // pair index within row
        int f = jp >> 3, off = jp & 7;
        out[(size_t)f * SLICE_U + (size_t)v * 8 + off] = packbf2(v2.x, v2.y);
    }
}

// W1 [k][n] fp32 -> Wt [n][k] bf16 (dense, for MFMA B-frag contiguity)
__global__ void k_wt(const float* __restrict__ W, unsigned short* __restrict__ Wt) {
    int i = blockIdx.x * blockDim.x + threadIdx.x;   // 16384
    int k = i >> 7, n = i & 127;
    Wt[n * 128 + k] = f2bf(W[i]);
}

// ---------------------------------------------------------------------------
__global__ void k_count(const int* __restrict__ dst, int* __restrict__ indeg, int E) {
    int i = blockIdx.x * blockDim.x + threadIdx.x;
    if (i < E) atomicAdd(&indeg[dst[i]], 1);
}

__global__ void k_dinv(const int* __restrict__ indeg, float* __restrict__ dinv, int n) {
    int i = blockIdx.x * blockDim.x + threadIdx.x;
    if (i < n) dinv[i] = rsqrtf((float)(indeg[i] + 1));
}

__global__ void k_scan1(const int* __restrict__ in, int* __restrict__ out,
                        int* __restrict__ bsums, int n) {
    __shared__ int lds[256];
    int blk = blockIdx.x, t = threadIdx.x;
    int base = blk * SCAN_BLK + t * 4;
    int v[4];
#pragma unroll
    for (int i = 0; i < 4; ++i) v[i] = (base + i < n) ? in[base + i] : 0;
    int local = v[0] + v[1] + v[2] + v[3];
    lds[t] = local;
    __syncthreads();
    for (int off = 1; off < 256; off <<= 1) {
        int x = lds[t];
        int y = (t >= off) ? lds[t - off] : 0;
        __syncthreads();
        lds[t] = x + y;
        __syncthreads();
    }
    int excl = lds[t] - local;
    if (t == 255) bsums[blk] = lds[255];
    int run = excl;
#pragma unroll
    for (int i = 0; i < 4; ++i) {
        if (base + i < n) { out[base + i] = run; run += v[i]; }
    }
}

__global__ void k_scan2(int* __restrict__ bsums, int nb) {
    __shared__ int lds[256];
    int t = threadIdx.x;
    int orig = (t < nb) ? bsums[t] : 0;
    lds[t] = orig;
    __syncthreads();
    for (int off = 1; off < 256; off <<= 1) {
        int x = lds[t];
        int y = (t >= off) ? lds[t - off] : 0;
        __syncthreads();
        lds[t] = x + y;
        __syncthreads();
    }
    if (t < nb) bsums[t] = lds[t] - orig;
}

__global__ void k_scan3(int* __restrict__ rp, const int* __restrict__ boffs, int n, int E) {
    int i = blockIdx.x * blockDim.x + threadIdx.x;
    if (i < n) rp[i] += boffs[i / SCAN_BLK];
    if (i == n) rp[n] = E;
}

// fill CSR: edges[idx] = {src, w = dinv[d]*dinv[s]} packed int2
__global__ void k_fill(const int* __restrict__ src, const int* __restrict__ dst,
                       const int* __restrict__ rp, int* __restrict__ cursor,
                       int2* __restrict__ edges, const float* __restrict__ dinv, int E) {
    int i = blockIdx.x * blockDim.x + threadIdx.x;
    if (i < E) {
        int d = dst[i], s = src[i];
        int p = atomicAdd(&cursor[d], 1);
        int2 r; r.x = s; r.y = __float_as_int(dinv[d] * dinv[s]);
        edges[rp[d] + p] = r;
    }
}

// ---------------------------------------------------------------------------
// XCD-sliced gather-aggregate: slice f = blockIdx & 7 (lands on XCD f, whose L2
// holds that 3.2MB feature slice). Wave = 8 groups x 8 lanes; group covers the
// 32B row-slice, groups stride the edge list by 8. Edge records streamed nt.
#define AGGS_BODY(X2)                                                            \
    int lane = threadIdx.x & 63;                                                 \
    int wv   = threadIdx.x >> 6;                                                 \
    int f    = blockIdx.x & 7;                                                   \
    int v    = ((blockIdx.x >> 3) << 2) + wv;                                    \
    int grp  = lane >> 3;                                                        \
    int fl   = lane & 7;                                                         \
    const unsigned* Xs = X2 + (size_t)f * SLICE_U;                               \
    float dv = dinv[v];                                                          \
    int e0 = rp[v], deg = rp[v + 1] - e0;                                        \
    float a0 = 0.f, a1 = 0.f;                                                    \
    if (grp == 0) {                                                              \
        unsigned u = Xs[(size_t)v * 8 + fl];                                     \
        float ws = dv * dv;                                                      \
        a0 = ws * bflo(u); a1 = ws * bfhi(u);                                    \
    }                                                                            \
    int i = grp;                                                                 \
    bool h0 = (i < deg);                                                         \
    long long rec = 0;                                                           \
    if (h0) rec = ldnt64(edges + e0 + i);                                        \
    while (h0) {                                                                 \
        bool h1 = (i + 8 < deg);                                                 \
        long long rec1 = 0;                                                      \
        if (h1) rec1 = ldnt64(edges + e0 + i + 8);                               \
        int s   = (int)(rec & 0xffffffffll);                                     \
        float w = __int_as_float((int)(rec >> 32));                              \
        unsigned u = Xs[(size_t)s * 8 + fl];                                     \
        a0 += w * bflo(u); a1 += w * bfhi(u);                                    \
        i += 8; rec = rec1; h0 = h1;                                             \
    }                                                                            \
    _Pragma("unroll")                                                            \
    for (int off = 8; off < 64; off <<= 1) {                                     \
        a0 += __shfl_xor(a0, off, 64);                                           \
        a1 += __shfl_xor(a1, off, 64);                                           \
    }

__global__ __launch_bounds__(256) void k_aggs1(
    const unsigned* __restrict__ X2, unsigned* __restrict__ O2,
    const int* __restrict__ rp, const int2* __restrict__ edges,
    const float* __restrict__ dinv)
{
    AGGS_BODY(X2)
    if (grp == 0)
        O2[(size_t)f * SLICE_U + (size_t)v * 8 + fl] = packbf2(a0, a1);
}

__global__ __launch_bounds__(256) void k_aggs2(
    const unsigned* __restrict__ X2,
    const int* __restrict__ rp, const int2* __restrict__ edges,
    const float* __restrict__ dinv, const int* __restrict__ batch,
    float* __restrict__ P, int* __restrict__ cnt)
{
    AGGS_BODY(X2)
    int g = batch[v];
    if (grp == 0) {
        atomicAdd(&P[(size_t)g * FDIM + f * 16 + fl * 2],     a0);
        atomicAdd(&P[(size_t)g * FDIM + f * 16 + fl * 2 + 1], a1);
    }
    if (f == 0 && lane == 0) atomicAdd(&cnt[g], 1);
}

// ---------------------------------------------------------------------------
// B = relu(A @ W1 + b1), A and B in 16-feature sliced layout, Wt dense.
__global__ __launch_bounds__(256) void k_gemm_mfma(
    const unsigned short* __restrict__ A, const unsigned short* __restrict__ Wt,
    const float* __restrict__ bias, unsigned short* __restrict__ B)
{
    int lane = threadIdx.x & 63;
    int wv = threadIdx.x >> 6;
    size_t row0 = (size_t)blockIdx.x * 64 + (size_t)wv * 16;
    int r = lane & 15, g = lane >> 4;

    short8v af[4];
#pragma unroll
    for (int ks = 0; ks < 4; ++ks) {
        int fa  = 2 * ks + (g >> 1);          // slice of features ks*32+g*8
        int off = (g & 1) * 8;
        af[ks] = *(const short8v*)(A + (size_t)fa * SLICE_U * 2 + (row0 + r) * 16 + off);
    }

    f32x4 acc[8];
#pragma unroll
    for (int ct = 0; ct < 8; ++ct) {
        f32x4 a = {0.f, 0.f, 0.f, 0.f};
        const unsigned short* wrow = Wt + (ct * 16 + r) * FDIM + g * 8;
#pragma unroll
        for (int ks = 0; ks < 4; ++ks) {
            short8v bfr = *(const short8v*)(wrow + ks * 32);
            a = __builtin_amdgcn_mfma_f32_16x16x32_bf16(af[ks], bfr, a, 0, 0, 0);
        }
        acc[ct] = a;
    }

#pragma unroll
    for (int ct = 0; ct < 8; ++ct) {
        float bs = bias[ct * 16 + r];
#pragma unroll
        for (int i = 0; i < 4; ++i) {
            size_t row = row0 + g * 4 + i;
            if (row < N_NODES) {
                float vv = fmaxf(acc[ct][i] + bs, 0.f);
                // feature ct*16 + r -> slice ct, offset r
                B[(size_t)ct * SLICE_U * 2 + row * 16 + r] = f2bf(vv);
            }
        }
    }
}

// ---------------------------------------------------------------------------
__global__ void k_wcomb(const float* __restrict__ W2, const float* __restrict__ Wf,
                        const float* __restrict__ b2, const float* __restrict__ bf,
                        float* __restrict__ Wc, float* __restrict__ bc) {
    int idx = blockIdx.x * blockDim.x + threadIdx.x;
    if (idx < 128 * 32) {
        int k = idx >> 5, c = idx & 31;
        float acc = 0.0f;
        for (int m = 0; m < 128; ++m) acc += W2[k * 128 + m] * Wf[m * 32 + c];
        Wc[idx] = acc;
    }
    if (idx < 32) {
        float acc = bf[idx];
        for (int m = 0; m < 128; ++m) acc += b2[m] * Wf[m * 32 + idx];
        bc[idx] = acc;
    }
}

__global__ void k_final(const float* __restrict__ P, const int* __restrict__ cnt,
                        const float* __restrict__ Wc, const float* __restrict__ bc,
                        const float* __restrict__ bf, float* __restrict__ out) {
    __shared__ float p[128];
    int g = blockIdx.x, t = threadIdx.x;
    int c_ = cnt[g];
    float inv = (c_ > 0) ? 1.0f / (float)c_ : 0.0f;
    p[t] = P[(size_t)g * FDIM + t] * inv;
    __syncthreads();
    if (t < N_CLASSES) {
        float acc = (c_ > 0) ? bc[t] : bf[t];
#pragma unroll
        for (int k = 0; k < 128; ++k) acc = fmaf(p[k], Wc[k * 32 + t], acc);
        out[(size_t)g * N_CLASSES + t] = acc;
    }
}

// ---------------------------------------------------------------------------
extern "C" void kernel_launch(void* const* d_in, const int* in_sizes, int n_in,
                              void* d_out, int out_size, void* d_ws, size_t ws_size,
                              hipStream_t stream) {
    const float* x    = (const float*)d_in[0];
    const int*   ei   = (const int*)d_in[1];
    const int*   batch= (const int*)d_in[2];
    const float* W1   = (const float*)d_in[3];
    const float* b1   = (const float*)d_in[4];
    const float* W2   = (const float*)d_in[5];
    const float* b2   = (const float*)d_in[6];
    const float* Wf   = (const float*)d_in[7];
    const float* bf   = (const float*)d_in[8];
    const int* src = ei;
    const int* dst = ei + N_EDGES;

    char* w = (char*)d_ws;
    auto alloc = [&](size_t bytes) { char* p = w; w += (bytes + 255) & ~255ull; return p; };
    int*      indeg  = (int*)     alloc((size_t)N_NODES * 4);
    float*    dinv   = (float*)   alloc((size_t)N_NODES * 4);
    int*      rp     = (int*)     alloc((size_t)(N_NODES + 1) * 4);
    int*      cursor = (int*)     alloc((size_t)N_NODES * 4);
    int*      bsums  = (int*)     alloc(1024 * 4);
    int2*     edges  = (int2*)    alloc((size_t)N_EDGES * 8);
    unsigned* xh     = (unsigned*)alloc((size_t)SLICE_U * 8 * 4);   // sliced bf16x2
    unsigned* Ab     = (unsigned*)alloc((size_t)SLICE_U * 8 * 4);
    unsigned* Bb     = (unsigned*)alloc((size_t)SLICE_U * 8 * 4);
    unsigned short* Wt = (unsigned short*)alloc(128 * 128 * 2);
    float*    P      = (float*)   alloc((size_t)N_GRAPHS * FDIM * 4);
    int*      cnt    = (int*)     alloc((size_t)N_GRAPHS * 4);
    float*    Wc     = (float*)   alloc(128 * 32 * 4);
    float*    bc     = (float*)   alloc(32 * 4);

    hipMemsetAsync(indeg,  0, (size_t)N_NODES * 4, stream);
    hipMemsetAsync(cursor, 0, (size_t)N_NODES * 4, stream);
    hipMemsetAsync(P,      0, (size_t)N_GRAPHS * FDIM * 4, stream);
    hipMemsetAsync(cnt,    0, (size_t)N_GRAPHS * 4, stream);

    const int nbScan = (N_NODES + SCAN_BLK - 1) / SCAN_BLK;   // 98

    // input conversions (independent of CSR build)
    k_f2bf<<<(N_NODES * 64 + 255) / 256, 256, 0, stream>>>(x, xh, N_NODES * 64);
    k_wt  <<<64, 256, 0, stream>>>(W1, Wt);

    // CSR build
    k_count<<<(N_EDGES + 255) / 256, 256, 0, stream>>>(dst, indeg, N_EDGES);
    k_dinv <<<(N_NODES + 255) / 256, 256, 0, stream>>>(indeg, dinv, N_NODES);
    k_scan1<<<nbScan, 256, 0, stream>>>(indeg, rp, bsums, N_NODES);
    k_scan2<<<1, 256, 0, stream>>>(bsums, nbScan);
    k_scan3<<<(N_NODES + 1 + 255) / 256, 256, 0, stream>>>(rp, bsums, N_NODES, N_EDGES);
    k_fill <<<(N_EDGES + 255) / 256, 256, 0, stream>>>(src, dst, rp, cursor, edges, dinv, N_EDGES);

    // layer 1: XCD-sliced aggregate, then MFMA GEMM + bias + relu (sliced A/B)
    k_aggs1<<<(N_NODES / 4) * 8, 256, 0, stream>>>(xh, Ab, rp, edges, dinv);
    k_gemm_mfma<<<M_PAD / 64, 256, 0, stream>>>((const unsigned short*)Ab, Wt, b1,
                                                (unsigned short*)Bb);

    // classifier weight folding (tiny, independent)
    k_wcomb<<<16, 256, 0, stream>>>(W2, Wf, b2, bf, Wc, bc);

    // layer 2 XCD-sliced aggregation fused with mean-pool accumulation
    k_aggs2<<<(N_NODES / 4) * 8, 256, 0, stream>>>(Bb, rp, edges, dinv, batch, P, cnt);

    // final: mean, fold through Wc=W2@Wf, write [1024,32]
    k_final<<<N_GRAPHS, 128, 0, stream>>>(P, cnt, Wc, bc, bf, (float*)d_out);
}